// Round 1
// baseline (156.611 us; speedup 1.0000x reference)
//
#include <hip/hip_runtime.h>
#include <math.h>

// Whiten: per-(b,c) mean/std normalization over the 224x224 slice.
// B=64, C=32, H=W=224 -> 2048 slices of 50176 fp32 each.
// Strategy: one 1024-thread block per slice; stage the whole slice in
// registers (12 x float4 per thread + 256-thread tail), block-reduce
// sum/sumsq, then write the normalized values from registers.
// HBM traffic = 1 read + 1 write = 822 MB total (the minimum).

namespace {
constexpr int kHW      = 224 * 224;                   // 50176
constexpr int kHW4     = kHW / 4;                     // 12544 float4 per slice
constexpr int kThreads = 1024;
constexpr int kFullIt  = kHW4 / kThreads;             // 12
constexpr int kExtra   = kHW4 - kFullIt * kThreads;   // 256 tail float4
constexpr float kMinDev = 1.0f / 224.0f;              // 1/sqrt(H*W), H*W=224^2
}

__global__ __launch_bounds__(kThreads, 1)
void whiten_fused(const float* __restrict__ x, float* __restrict__ y) {
    const int bc  = blockIdx.x;
    const int tid = threadIdx.x;
    const float4* __restrict__ xs =
        reinterpret_cast<const float4*>(x) + (size_t)bc * kHW4;
    float4* __restrict__ ys =
        reinterpret_cast<float4*>(y) + (size_t)bc * kHW4;

    // ---- load entire slice into registers (max memory-level parallelism) ----
    float4 v[kFullIt];
    float4 ve = make_float4(0.f, 0.f, 0.f, 0.f);
    const bool extra = (tid < kExtra);
#pragma unroll
    for (int i = 0; i < kFullIt; ++i) v[i] = xs[tid + i * kThreads];
    if (extra) ve = xs[kFullIt * kThreads + tid];

    // ---- per-thread partial sum / sumsq ----
    float s = 0.f, ss = 0.f;
#pragma unroll
    for (int i = 0; i < kFullIt; ++i) {
        s += v[i].x + v[i].y + v[i].z + v[i].w;
        ss = fmaf(v[i].x, v[i].x, ss);
        ss = fmaf(v[i].y, v[i].y, ss);
        ss = fmaf(v[i].z, v[i].z, ss);
        ss = fmaf(v[i].w, v[i].w, ss);
    }
    // tail contributes 0 for non-extra threads (ve zero-initialized)
    s += ve.x + ve.y + ve.z + ve.w;
    ss = fmaf(ve.x, ve.x, ss);
    ss = fmaf(ve.y, ve.y, ss);
    ss = fmaf(ve.z, ve.z, ss);
    ss = fmaf(ve.w, ve.w, ss);

    // ---- wave64 butterfly reduction ----
#pragma unroll
    for (int off = 32; off >= 1; off >>= 1) {
        s  += __shfl_down(s, off, 64);
        ss += __shfl_down(ss, off, 64);
    }

    // ---- cross-wave reduction via LDS (16 waves) ----
    __shared__ float wred_s[kThreads / 64];
    __shared__ float wred_q[kThreads / 64];
    __shared__ float stats[2];
    const int wid  = tid >> 6;
    const int lane = tid & 63;
    if (lane == 0) { wred_s[wid] = s; wred_q[wid] = ss; }
    __syncthreads();
    if (tid == 0) {
        float S = 0.f, SS = 0.f;
#pragma unroll
        for (int i = 0; i < kThreads / 64; ++i) { S += wred_s[i]; SS += wred_q[i]; }
        const float mean = S * (1.0f / kHW);
        float var = (SS - S * mean) * (1.0f / (kHW - 1));
        var = fmaxf(var, 0.f);
        const float dev = fmaxf(sqrtf(var), kMinDev);
        stats[0] = mean;
        stats[1] = 1.0f / dev;
    }
    __syncthreads();
    const float mean = stats[0];
    const float rcp  = stats[1];

    // ---- normalize from registers and store ----
#pragma unroll
    for (int i = 0; i < kFullIt; ++i) {
        float4 o;
        o.x = (v[i].x - mean) * rcp;
        o.y = (v[i].y - mean) * rcp;
        o.z = (v[i].z - mean) * rcp;
        o.w = (v[i].w - mean) * rcp;
        ys[tid + i * kThreads] = o;
    }
    if (extra) {
        float4 o;
        o.x = (ve.x - mean) * rcp;
        o.y = (ve.y - mean) * rcp;
        o.z = (ve.z - mean) * rcp;
        o.w = (ve.w - mean) * rcp;
        ys[kFullIt * kThreads + tid] = o;
    }
}

extern "C" void kernel_launch(void* const* d_in, const int* in_sizes, int n_in,
                              void* d_out, int out_size, void* d_ws, size_t ws_size,
                              hipStream_t stream) {
    (void)in_sizes; (void)n_in; (void)d_ws; (void)ws_size; (void)out_size;
    const float* x = reinterpret_cast<const float*>(d_in[0]);
    float* y = reinterpret_cast<float*>(d_out);
    const int nSlices = 64 * 32;  // B * C
    whiten_fused<<<nSlices, kThreads, 0, stream>>>(x, y);
}